// Round 9
// baseline (322.644 us; speedup 1.0000x reference)
//
#include <hip/hip_runtime.h>
#include <math.h>

#define B_ 8
#define N_ 2048
#define K_ 8
#define IN_ 5
#define BN_ (B_*N_)
#define NEDGE_ (BN_*K_)
#define GRP 8
#define SEG_ 32
#define CSEG_ (N_/SEG_)   // 64 candidates per segment
#define CHUNKS_ (N_/GRP)  // 256 combine-blocks per batch
#define FIXS_ 1048576.0   // 2^20 fixed-point scale for BN atomics

typedef unsigned short ushort8_ __attribute__((ext_vector_type(8)));
typedef short bf16x8_ __attribute__((ext_vector_type(8)));
typedef float f32x4_ __attribute__((ext_vector_type(4)));

// float -> bf16 (RNE), bf16 -> float
__device__ inline unsigned short f2bf(float f) {
    unsigned int u = __float_as_uint(f);
    u += 0x7fffu + ((u >> 16) & 1u);
    return (unsigned short)(u >> 16);
}
__device__ inline float bf2f(unsigned short h) {
    return __uint_as_float(((unsigned int)h) << 16);
}

// ordered-float: monotone map f32 -> u32 (3 VALU ops)
__device__ inline unsigned int ord_f32(float f) {
    unsigned int u = __float_as_uint(f);
    return u ^ (((unsigned int)((int)u >> 31)) | 0x80000000u);
}

// BN scale/shift from fixed-point accumulators: acc = [sum[C] | ssq[C]] * 2^20
__device__ inline void bn_from_acc(const unsigned long long* __restrict__ acc, int C,
                                   const float* __restrict__ g, const float* __restrict__ be,
                                   int k, float& sc, float& sh) {
    double inv = 1.0 / (FIXS_ * (double)NEDGE_);
    double mean = (double)(long long)acc[k] * inv;
    double var  = (double)(long long)acc[C + k] * inv - mean*mean;
    float s = g[k] * rsqrtf((float)var + 1e-5f);
    sc = s;
    sh = be[k] - (float)mean * s;
}

// ---------------- kNN phase 1: per-segment top-8; 32-bit pair insert, scalar candidate loads ----------------
__global__ __launch_bounds__(256) void knn_part(const float4* __restrict__ P4,
                                                unsigned long long* __restrict__ part) {
    int tid = threadIdx.x;
    int bblk = blockIdx.x >> 3;         // batch id: PROVABLY uniform (8 blocks per batch)
    int q = blockIdx.x * 256 + tid;
    int nloc = q & (N_-1);
    int seg = blockIdx.y;

    float4 qp = P4[q];
    float qx2 = -2.0f*qp.x, qy2 = -2.0f*qp.y, qz2 = -2.0f*qp.z;
    float qsq = qp.w;

    unsigned int bd[K_], bi[K_];
#pragma unroll
    for (int k = 0; k < K_; ++k) { bd[k] = 0xFFFFFFFFu; bi[k] = 0xFFFFFFFFu; }

    const float4* __restrict__ cb = P4 + ((size_t)bblk << 11) + (size_t)seg*CSEG_;  // uniform base -> s_load
    int jbase = seg * CSEG_;

#pragma unroll 4
    for (int jj = 0; jj < CSEG_; ++jj) {
        float4 c = cb[jj];
        float d = qsq + c.w;
        d = fmaf(qx2, c.x, d);
        d = fmaf(qy2, c.y, d);
        d = fmaf(qz2, c.z, d);
        int jg = jbase + jj;
        d = (jg == nloc) ? INFINITY : d;   // self-exclusion; INF expelled by >=8 finite cands
        unsigned int cd = ord_f32(d);
        unsigned int ci = (unsigned int)jg;
        // stable unconditional insert: strict < keeps equal-d entries in idx (scan) order
        // -> exact (d, idx) lexicographic semantics at 5 VALU/position
#pragma unroll
        for (int p = 0; p < K_; ++p) {
            bool lt = cd < bd[p];
            unsigned int nd = lt ? cd : bd[p];
            unsigned int xd = lt ? bd[p] : cd;
            unsigned int ni = lt ? ci : bi[p];
            unsigned int xi = lt ? bi[p] : ci;
            bd[p] = nd; cd = xd; bi[p] = ni; ci = xi;
        }
    }
    unsigned long long* op = part + ((size_t)seg * BN_ + q) * K_;
#pragma unroll
    for (int k = 0; k < K_; ++k)
        op[k] = ((unsigned long long)bd[k] << 32) | bi[k];
}

// ---------------- kNN phase 2: merge SEG_ sorted 8-lists ----------------
__global__ __launch_bounds__(128) void knn_merge(const unsigned long long* __restrict__ part,
                                                 int* __restrict__ src) {
    int q = blockIdx.x * 128 + threadIdx.x;
    int b = q / N_;
    unsigned long long best[K_];
#pragma unroll
    for (int k = 0; k < K_; ++k) best[k] = ~0ull;
    for (int s = 0; s < SEG_; ++s) {
        const unsigned long long* lp = part + ((size_t)s * BN_ + q) * K_;
#pragma unroll
        for (int k = 0; k < K_; ++k) {
            unsigned long long key = lp[k];
            if (key >= best[K_-1]) break;   // lists sorted ascending -> rest are larger
            unsigned long long cur = key;
#pragma unroll
            for (int p = 0; p < K_; ++p) {
                unsigned long long lo = best[p] < cur ? best[p] : cur;
                unsigned long long hi = best[p] < cur ? cur : best[p];
                best[p] = lo; cur = hi;
            }
        }
    }
#pragma unroll
    for (int k = 0; k < K_; ++k)
        src[(size_t)q*K_ + k] = b*N_ + (int)(best[k] & 0xFFFFFFFFu);
}

// ---------------- layer-1 input cast + packed P4 build (runs FIRST) ----------------
__global__ __launch_bounds__(256) void cast_split(const float* __restrict__ X,
                                                  unsigned short* __restrict__ Xh,
                                                  unsigned short* __restrict__ Xl,
                                                  float4* __restrict__ P4,
                                                  int Kin, int Kpad, int total8) {
    int t = blockIdx.x * 256 + threadIdx.x;
    if (t < total8) {
        int vpr = Kpad >> 3;
        int m = t / vpr;
        int k0 = (t % vpr) * 8;
        ushort8_ vh, vl;
#pragma unroll
        for (int j = 0; j < 8; ++j) {
            int k = k0 + j;
            float v = (k < Kin) ? X[(size_t)m*Kin + k] : 0.0f;
            unsigned short h = f2bf(v);
            vh[j] = h;
            vl[j] = f2bf(v - bf2f(h));
        }
        *(ushort8_*)(Xh + (size_t)m*Kpad + k0) = vh;
        *(ushort8_*)(Xl + (size_t)m*Kpad + k0) = vl;
    }
    if (t < BN_) {
        const float* p = X + (size_t)t*Kin;
        float x = p[0], y = p[1], z = p[2];
        P4[t] = make_float4(x, y, z, x*x + y*y + z*z);
    }
}

// ---------------- fused weight prep: WT split-bf16 (BN fold from accumulators) + c' vector ----------------
__global__ __launch_bounds__(256) void prep_layer(const float* __restrict__ W,
                                                  const unsigned long long* __restrict__ acc_prev,
                                                  const float* __restrict__ g_prev,
                                                  const float* __restrict__ be_prev,
                                                  const float* __restrict__ bias,
                                                  unsigned short* __restrict__ WTh,
                                                  unsigned short* __restrict__ WTl,
                                                  float* __restrict__ cvec,
                                                  int Cin, int C, int Kpad) {
    int idx = blockIdx.x * 256 + threadIdx.x;
    int nWT = 2*C*Kpad;                  // multiple of 256 -> branch below is block-uniform
    if (idx < nWT) {
        int n = idx / Kpad;
        int k = idx % Kpad;
        float val = 0.0f;
        if (k < Cin) {
            float s = 1.0f;
            if (acc_prev) { float sc, sh; bn_from_acc(acc_prev, Cin, g_prev, be_prev, k, sc, sh); s = sc; }
            if (n < C) val = s * (W[(size_t)k*C + n] - W[(size_t)(Cin+k)*C + n]);
            else       val = s * W[(size_t)(Cin+k)*C + (n - C)];
        }
        unsigned short h = f2bf(val);
        WTh[(size_t)n*Kpad + k] = h;
        WTl[(size_t)n*Kpad + k] = f2bf(val - bf2f(h));
    } else {
        // cvec block: all threads of this block are here (nWT % 256 == 0)
        __shared__ float sh_s[256];
        int c = idx - nWT;
        if (acc_prev && c < Cin) {
            float sc, sh; bn_from_acc(acc_prev, Cin, g_prev, be_prev, c, sc, sh);
            sh_s[c] = sh;
        }
        __syncthreads();
        if (c < C) {
            float a = bias[c];
            if (acc_prev)
                for (int d = 0; d < Cin; ++d) a += sh_s[d] * W[(size_t)d*C + c];
            cvec[c] = a;
        }
    }
}

// ---------------- split-bf16 MFMA GEMM: PQ[M][Ntot] = X[M][K] @ WT^T, 128x128 tile, BK=32 ----------------
// 1-D grid, XCD-swizzled: all col-blocks of a row-panel land on XCD (y%8) for A-panel L2 reuse
__global__ __launch_bounds__(256) void mfma_dual(const unsigned short* __restrict__ Xh,
                                                 const unsigned short* __restrict__ Xl,
                                                 const unsigned short* __restrict__ WTh,
                                                 const unsigned short* __restrict__ WTl,
                                                 float* __restrict__ PQ, int K, int Ntot,
                                                 int gx) {
    __shared__ unsigned short sXh[128*32], sXl[128*32], sWh[128*32], sWl[128*32];
    int n = blockIdx.x;
    int by = (n & 7) + 8*(n/(8*gx));    // y%8 == n%8 == XCD
    int bx = (n >> 3) % gx;
    int tid = threadIdx.x, l = tid & 63, w = tid >> 6;
    int wr = w >> 1, wc = w & 1;                       // 2x2 waves -> 64x64 per wave
    int bm = by * 128, bn0 = bx * 128;

    f32x4_ acc[4][4];
#pragma unroll
    for (int i = 0; i < 4; ++i)
#pragma unroll
        for (int j = 0; j < 4; ++j) acc[i][j] = (f32x4_){0.f, 0.f, 0.f, 0.f};

    for (int k0 = 0; k0 < K; k0 += 32) {
#pragma unroll
        for (int i = 0; i < 2; ++i) {
            int idx = tid + i*256;                     // 0..511
            int row = idx >> 2;                        // 0..127
            int col0 = (idx & 3) * 8;                  // 0,8,16,24
            size_t gxo = (size_t)(bm  + row)*K + k0 + col0;
            size_t gwo = (size_t)(bn0 + row)*K + k0 + col0;
            int lo_ = ((row << 6) | (col0 << 1)) ^ ((row & 7) << 4);  // XOR swizzle
            *(ushort8_*)((char*)sXh + lo_) = *(const ushort8_*)(Xh + gxo);
            *(ushort8_*)((char*)sXl + lo_) = *(const ushort8_*)(Xl + gxo);
            *(ushort8_*)((char*)sWh + lo_) = *(const ushort8_*)(WTh + gwo);
            *(ushort8_*)((char*)sWl + lo_) = *(const ushort8_*)(WTl + gwo);
        }
        __syncthreads();

        int kb = (l >> 4) << 4;                        // byte offset of this lane's 8 k-elems
        bf16x8_ bh[4], bl4[4];
#pragma unroll
        for (int nf = 0; nf < 4; ++nf) {
            int rn = wc*64 + nf*16 + (l & 15);
            int o = ((rn << 6) | kb) ^ ((rn & 7) << 4);
            bh[nf]  = *(const bf16x8_*)((const char*)sWh + o);
            bl4[nf] = *(const bf16x8_*)((const char*)sWl + o);
        }
#pragma unroll
        for (int mf = 0; mf < 4; ++mf) {
            int rm = wr*64 + mf*16 + (l & 15);
            int o = ((rm << 6) | kb) ^ ((rm & 7) << 4);
            bf16x8_ ah = *(const bf16x8_*)((const char*)sXh + o);
            bf16x8_ al = *(const bf16x8_*)((const char*)sXl + o);
#pragma unroll
            for (int nf = 0; nf < 4; ++nf) {
                acc[mf][nf] = __builtin_amdgcn_mfma_f32_16x16x32_bf16(ah, bh[nf],  acc[mf][nf], 0, 0, 0);
                acc[mf][nf] = __builtin_amdgcn_mfma_f32_16x16x32_bf16(ah, bl4[nf], acc[mf][nf], 0, 0, 0);
                acc[mf][nf] = __builtin_amdgcn_mfma_f32_16x16x32_bf16(al, bh[nf],  acc[mf][nf], 0, 0, 0);
            }
        }
        __syncthreads();
    }

    int r0 = (l >> 4) << 2, cB = l & 15;
#pragma unroll
    for (int mf = 0; mf < 4; ++mf)
#pragma unroll
        for (int nf = 0; nf < 4; ++nf) {
            int col = bn0 + wc*64 + nf*16 + cB;
#pragma unroll
            for (int reg = 0; reg < 4; ++reg) {
                int row = bm + wr*64 + mf*16 + r0 + reg;
                PQ[(size_t)row*Ntot + col] = acc[mf][nf][reg];
            }
        }
}

// ---------------- edge combine: h = P[dst] + Q[src] + c ; lrelu; per-dst max -> split-bf16 X_next;
//                  BN stats via fixed-point i64 atomics (deterministic); per-block partial max ----------------
__global__ void combine_kernel(const float* __restrict__ P, const float* __restrict__ Q,
                               const float* __restrict__ cvec, const int* __restrict__ src,
                               unsigned short* __restrict__ Xh_out, unsigned short* __restrict__ Xl_out,
                               unsigned long long* __restrict__ acc, float* __restrict__ gpart,
                               int C, int S) {
    int pb = blockIdx.x;
    int lb = (pb & 7) * CHUNKS_ + (pb >> 3);   // bijective: XCD (pb%8) gets all blocks of batch pb%8
    int c = threadIdx.x;                 // blockDim.x == C
    int i0 = lb * GRP;
    float cv = cvec[c];
    float sum = 0.f, ssq = 0.f;
    float bmx = -INFINITY;
    for (int g = 0; g < GRP; ++g) {
        int i = i0 + g;
        float p = P[(size_t)i*S + c] + cv;
        float mx = -INFINITY;
#pragma unroll
        for (int k = 0; k < K_; ++k) {
            int s = src[(size_t)i*K_ + k];
            float h = p + Q[(size_t)s*S + c];
            float l = (h >= 0.f) ? h : 0.2f*h;
            sum += l; ssq += l*l;
            mx = fmaxf(mx, l);
        }
        if (Xh_out) {                    // next layer's input, split-bf16 (Kpad_next == C)
            unsigned short hh = f2bf(mx);
            Xh_out[(size_t)i*C + c] = hh;
            Xl_out[(size_t)i*C + c] = f2bf(mx - bf2f(hh));
        }
        bmx = fmaxf(bmx, mx);
    }
    gpart[(size_t)lb*C + c] = bmx;
    // fixed-point i64 atomics: integer adds commute exactly -> deterministic
    long long qs = llrint((double)sum * FIXS_);
    long long qq = llrint((double)ssq * FIXS_);
    atomicAdd(&acc[c],     (unsigned long long)qs);
    atomicAdd(&acc[C + c], (unsigned long long)qq);
}

// ---------------- fused global max-pool finalize (BN affine computed from accumulators) ----------------
__global__ __launch_bounds__(1024) void gmax_finalize(
        const float* __restrict__ gp1, const float* __restrict__ gp2, const float* __restrict__ gp3,
        const unsigned long long* __restrict__ a1, const float* __restrict__ g1, const float* __restrict__ be1,
        const unsigned long long* __restrict__ a2, const float* __restrict__ g2, const float* __restrict__ be2,
        const unsigned long long* __restrict__ a3, const float* __restrict__ g3, const float* __restrict__ be3,
        float* __restrict__ gfeat) {
    int b = blockIdx.x, grp = blockIdx.y;
    const float *gp, *g, *be; const unsigned long long* ac; int C, c0, coff;
    if (grp == 0)      { gp = gp1; ac = a1; g = g1; be = be1; C = 64;  c0 = 0;          coff = 0;   }
    else if (grp <= 2) { gp = gp2; ac = a2; g = g2; be = be2; C = 128; c0 = (grp-1)*64; coff = 64;  }
    else               { gp = gp3; ac = a3; g = g3; be = be3; C = 256; c0 = (grp-3)*64; coff = 192; }
    int cl = threadIdx.x & 63;
    int stripe = threadIdx.x >> 6;   // 0..15
    int c = c0 + cl;
    float mx = -INFINITY;
    for (int ch = stripe; ch < CHUNKS_; ch += 16)
        mx = fmaxf(mx, gp[((size_t)b*CHUNKS_ + ch)*C + c]);
    __shared__ float red[16][64];
    red[stripe][cl] = mx;
    __syncthreads();
    for (int off = 8; off > 0; off >>= 1) {
        if (stripe < off) red[stripe][cl] = fmaxf(red[stripe][cl], red[stripe+off][cl]);
        __syncthreads();
    }
    if (stripe == 0) {
        float sc, sh; bn_from_acc(ac, C, g, be, c, sc, sh);
        gfeat[b*448 + coff + c] = sc*red[0][cl] + sh;
    }
}

// ---------------- head part 1: H = BN(lrelu(gfeat@Wf1 + bf1)) ----------------
__global__ __launch_bounds__(256) void final1(const float* __restrict__ gfeat,
                                              const float* __restrict__ Wf1, const float* __restrict__ bf1,
                                              const float* __restrict__ gf, const float* __restrict__ bef,
                                              float* __restrict__ H) {
    __shared__ float gfs[B_][448];
    __shared__ float red[4][64][B_];
    int t = threadIdx.x;
    int cl = t & 63;
    int stripe = t >> 6;                 // 0..3
    int c = blockIdx.x * 64 + cl;
    for (int e = t; e < B_*448; e += 256) gfs[e/448][e%448] = gfeat[e];
    __syncthreads();
    float acc[B_] = {};
    for (int d = stripe*112; d < stripe*112 + 112; ++d) {
        float w = Wf1[(size_t)d*512 + c];
#pragma unroll
        for (int r = 0; r < B_; ++r) acc[r] += gfs[r][d] * w;
    }
#pragma unroll
    for (int r = 0; r < B_; ++r) red[stripe][cl][r] = acc[r];
    __syncthreads();
    if (stripe == 0) {
        float v[B_];
        float b1v = bf1[c];
#pragma unroll
        for (int r = 0; r < B_; ++r) {
            float a = red[0][cl][r] + red[1][cl][r] + red[2][cl][r] + red[3][cl][r] + b1v;
            v[r] = (a >= 0.f) ? a : 0.2f*a;
        }
        float mean = 0.f;
#pragma unroll
        for (int r = 0; r < B_; ++r) mean += v[r];
        mean *= (1.0f/B_);
        float var = 0.f;
#pragma unroll
        for (int r = 0; r < B_; ++r) { float dd = v[r] - mean; var += dd*dd; }
        var *= (1.0f/B_);
        float sc = gf[c] * rsqrtf(var + 1e-5f);
        float sh = bef[c] - mean*sc;
#pragma unroll
        for (int r = 0; r < B_; ++r) H[(size_t)r*512 + c] = v[r]*sc + sh;
    }
}

// ---------------- head part 2: out = H @ Wf2 + bf2 ----------------
__global__ __launch_bounds__(128) void final2(const float* __restrict__ H,
                                              const float* __restrict__ Wf2, const float* __restrict__ bf2,
                                              float* __restrict__ out) {
    int b = blockIdx.x, c = threadIdx.x;
    __shared__ float hs[512];
    for (int e = c; e < 512; e += 128) hs[e] = H[(size_t)b*512 + e];
    __syncthreads();
    float a = bf2[c];
    for (int d = 0; d < 512; ++d) a += hs[d] * Wf2[(size_t)d*128 + c];
    out[b*128 + c] = a;
}

// ---------------- host side ----------------
static void run_layer(int Kpad, int C,
                      const float* W, const float* g, const float* be, const float* b,
                      const unsigned long long* acc_prev, const float* g_prev, const float* be_prev,
                      float* PQ, const unsigned short* Xh_in, const unsigned short* Xl_in,
                      unsigned short* Xh_next, unsigned short* Xl_next,
                      unsigned short* WTh, unsigned short* WTl, float* cvec,
                      const int* src, unsigned long long* acc_out, float* gpart,
                      hipStream_t stream) {
    int Cin = (acc_prev == nullptr) ? IN_ : Kpad;   // layer1: Cin=5, else Cin==Kpad
    int nPrep = 2*C*Kpad + C;
    int gx = 2*C/128;
    prep_layer<<<(nPrep + 255)/256, 256, 0, stream>>>(W, acc_prev, g_prev, be_prev, b,
                                                      WTh, WTl, cvec, Cin, C, Kpad);
    mfma_dual<<<gx*(BN_/128), 256, 0, stream>>>(Xh_in, Xl_in, WTh, WTl, PQ, Kpad, 2*C, gx);
    combine_kernel<<<BN_/GRP, C, 0, stream>>>(PQ, PQ + C, cvec, src, Xh_next, Xl_next, acc_out, gpart, C, 2*C);
}

extern "C" void kernel_launch(void* const* d_in, const int* in_sizes, int n_in,
                              void* d_out, int out_size, void* d_ws, size_t ws_size,
                              hipStream_t stream) {
    (void)in_sizes; (void)n_in; (void)out_size; (void)ws_size;
    const float* points = (const float*)d_in[0];
    const float* W1 = (const float*)d_in[1];  const float* b1 = (const float*)d_in[2];
    const float* g1 = (const float*)d_in[3];  const float* be1 = (const float*)d_in[4];
    const float* W2 = (const float*)d_in[5];  const float* b2 = (const float*)d_in[6];
    const float* g2 = (const float*)d_in[7];  const float* be2 = (const float*)d_in[8];
    const float* W3 = (const float*)d_in[9];  const float* b3 = (const float*)d_in[10];
    const float* g3 = (const float*)d_in[11]; const float* be3 = (const float*)d_in[12];
    const float* Wf1 = (const float*)d_in[13]; const float* bf1 = (const float*)d_in[14];
    const float* gf = (const float*)d_in[15];  const float* bef = (const float*)d_in[16];
    const float* Wf2 = (const float*)d_in[17]; const float* bf2 = (const float*)d_in[18];
    float* out = (float*)d_out;

    size_t off = 0;
    char* base = (char*)d_ws;
    auto carve = [&](size_t bytes) -> void* {
        void* p = base + off;
        off += (bytes + 255) & ~(size_t)255;
        return p;
    };
    int*   src     = (int*)  carve((size_t)NEDGE_ * 4);
    float* PQ      = (float*)carve((size_t)BN_ * 512 * 4);   // 32MB; also kNN partial overlay
    float* gp1     = (float*)carve((size_t)(BN_/GRP) * 64 * 4);
    float* gp2     = (float*)carve((size_t)(BN_/GRP) * 128 * 4);
    float* gp3     = (float*)carve((size_t)(BN_/GRP) * 256 * 4);
    unsigned short* XhA = (unsigned short*)carve((size_t)BN_ * 128 * 2);
    unsigned short* XlA = (unsigned short*)carve((size_t)BN_ * 128 * 2);
    unsigned short* XhB = (unsigned short*)carve((size_t)BN_ * 128 * 2);
    unsigned short* XlB = (unsigned short*)carve((size_t)BN_ * 128 * 2);
    unsigned short* WTh = (unsigned short*)carve((size_t)512 * 128 * 2);
    unsigned short* WTl = (unsigned short*)carve((size_t)512 * 128 * 2);
    float4* P4     = (float4*)carve((size_t)BN_ * 16);
    float* cvec    = (float*)carve(256 * 4);
    unsigned long long* accAll = (unsigned long long*)carve(896 * 8);  // [sum|ssq] x 64,128,256
    float* gfeat   = (float*)carve((size_t)B_ * 448 * 4);
    float* H       = (float*)carve((size_t)B_ * 512 * 4);

    unsigned long long* acc1 = accAll;          // 2*64
    unsigned long long* acc2 = accAll + 128;    // 2*128
    unsigned long long* acc3 = accAll + 384;    // 2*256

    // zero BN accumulators (graph-legal async memset; required every call for determinism)
    hipMemsetAsync(accAll, 0, 896 * 8, stream);

    // layer-1 cast + P4 pack first (knn reads P4)
    int total8 = BN_ * 32 / 8;
    cast_split<<<(total8 + 255)/256, 256, 0, stream>>>(points, XhA, XlA, P4, IN_, 32, total8);

    // kNN: phase-1 partials (SEG_*BN_*K_*8B = 32MB) overlay PQ (dead until first mfma_dual)
    unsigned long long* part = (unsigned long long*)PQ;
    knn_part<<<dim3(BN_/256, SEG_), 256, 0, stream>>>(P4, part);
    knn_merge<<<BN_/128, 128, 0, stream>>>(part, src);

    run_layer(32, 64,  W1, g1, be1, b1, nullptr, nullptr, nullptr,
              PQ, XhA, XlA, XhB, XlB, WTh, WTl, cvec, src, acc1, gp1, stream);
    run_layer(64, 128, W2, g2, be2, b2, acc1, g1, be1,
              PQ, XhB, XlB, XhA, XlA, WTh, WTl, cvec, src, acc2, gp2, stream);
    run_layer(128, 256, W3, g3, be3, b3, acc2, g2, be2,
              PQ, XhA, XlA, nullptr, nullptr, WTh, WTl, cvec, src, acc3, gp3, stream);

    gmax_finalize<<<dim3(B_, 7), 1024, 0, stream>>>(gp1, gp2, gp3,
                                                    acc1, g1, be1, acc2, g2, be2, acc3, g3, be3,
                                                    gfeat);

    final1<<<8, 256, 0, stream>>>(gfeat, Wf1, bf1, gf, bef, H);
    final2<<<8, 128, 0, stream>>>(H, Wf2, bf2, out);
}

// Round 10
// 220.359 us; speedup vs baseline: 1.4642x; 1.4642x over previous
//
#include <hip/hip_runtime.h>
#include <math.h>

#define B_ 8
#define N_ 2048
#define K_ 8
#define IN_ 5
#define BN_ (B_*N_)
#define NEDGE_ (BN_*K_)
#define GRP 8
#define SEG_ 32
#define CSEG_ (N_/SEG_)   // 64 candidates per segment
#define CHUNKS_ (N_/GRP)  // 256 combine-blocks per batch

typedef unsigned short ushort8_ __attribute__((ext_vector_type(8)));
typedef short bf16x8_ __attribute__((ext_vector_type(8)));
typedef float f32x4_ __attribute__((ext_vector_type(4)));

// float -> bf16 (RNE), bf16 -> float
__device__ inline unsigned short f2bf(float f) {
    unsigned int u = __float_as_uint(f);
    u += 0x7fffu + ((u >> 16) & 1u);
    return (unsigned short)(u >> 16);
}
__device__ inline float bf2f(unsigned short h) {
    return __uint_as_float(((unsigned int)h) << 16);
}

// ordered-float: monotone map f32 -> u32 (3 VALU ops)
__device__ inline unsigned int ord_f32(float f) {
    unsigned int u = __float_as_uint(f);
    return u ^ (((unsigned int)((int)u >> 31)) | 0x80000000u);
}

// ---------------- kNN phase 1: per-segment top-8; 32-bit pair insert, scalar candidate loads ----------------
__global__ __launch_bounds__(256) void knn_part(const float4* __restrict__ P4,
                                                unsigned long long* __restrict__ part) {
    int tid = threadIdx.x;
    int bblk = blockIdx.x >> 3;         // batch id: PROVABLY uniform (8 blocks per batch)
    int q = blockIdx.x * 256 + tid;
    int nloc = q & (N_-1);
    int seg = blockIdx.y;

    float4 qp = P4[q];
    float qx2 = -2.0f*qp.x, qy2 = -2.0f*qp.y, qz2 = -2.0f*qp.z;
    float qsq = qp.w;

    unsigned int bd[K_], bi[K_];
#pragma unroll
    for (int k = 0; k < K_; ++k) { bd[k] = 0xFFFFFFFFu; bi[k] = 0xFFFFFFFFu; }

    const float4* __restrict__ cb = P4 + ((size_t)bblk << 11) + (size_t)seg*CSEG_;  // uniform base -> s_load
    int jbase = seg * CSEG_;

#pragma unroll 8
    for (int jj = 0; jj < CSEG_; ++jj) {
        float4 c = cb[jj];
        float d = qsq + c.w;
        d = fmaf(qx2, c.x, d);
        d = fmaf(qy2, c.y, d);
        d = fmaf(qz2, c.z, d);
        int jg = jbase + jj;
        d = (jg == nloc) ? INFINITY : d;   // self-exclusion; INF expelled by >=8 finite cands
        unsigned int cd = ord_f32(d);
        unsigned int ci = (unsigned int)jg;
        // stable unconditional insert: strict < keeps equal-d entries in idx (scan) order
        // -> exact (d, idx) lexicographic semantics at 5 VALU/position
#pragma unroll
        for (int p = 0; p < K_; ++p) {
            bool lt = cd < bd[p];
            unsigned int nd = lt ? cd : bd[p];
            unsigned int xd = lt ? bd[p] : cd;
            unsigned int ni = lt ? ci : bi[p];
            unsigned int xi = lt ? bi[p] : ci;
            bd[p] = nd; cd = xd; bi[p] = ni; ci = xi;
        }
    }
    unsigned long long* op = part + ((size_t)seg * BN_ + q) * K_;
#pragma unroll
    for (int k = 0; k < K_; ++k)
        op[k] = ((unsigned long long)bd[k] << 32) | bi[k];
}

// ---------------- kNN phase 2: merge SEG_ sorted 8-lists ----------------
__global__ __launch_bounds__(128) void knn_merge(const unsigned long long* __restrict__ part,
                                                 int* __restrict__ src) {
    int q = blockIdx.x * 128 + threadIdx.x;
    int b = q / N_;
    unsigned long long best[K_];
#pragma unroll
    for (int k = 0; k < K_; ++k) best[k] = ~0ull;
    for (int s = 0; s < SEG_; ++s) {
        const unsigned long long* lp = part + ((size_t)s * BN_ + q) * K_;
#pragma unroll
        for (int k = 0; k < K_; ++k) {
            unsigned long long key = lp[k];
            if (key >= best[K_-1]) break;   // lists sorted ascending -> rest are larger
            unsigned long long cur = key;
#pragma unroll
            for (int p = 0; p < K_; ++p) {
                unsigned long long lo = best[p] < cur ? best[p] : cur;
                unsigned long long hi = best[p] < cur ? cur : best[p];
                best[p] = lo; cur = hi;
            }
        }
    }
#pragma unroll
    for (int k = 0; k < K_; ++k)
        src[(size_t)q*K_ + k] = b*N_ + (int)(best[k] & 0xFFFFFFFFu);
}

// ---------------- fused: layer-1 input cast + P4 pack + layer-1 weight prep (no BN deps) ----------------
__global__ __launch_bounds__(256) void cast_prep1(const float* __restrict__ X,
                                                  unsigned short* __restrict__ Xh,
                                                  unsigned short* __restrict__ Xl,
                                                  float4* __restrict__ P4,
                                                  const float* __restrict__ W1,
                                                  const float* __restrict__ b1,
                                                  unsigned short* __restrict__ WTh,
                                                  unsigned short* __restrict__ WTl,
                                                  float* __restrict__ cvec) {
    const int total8 = BN_ * 32 / 8;     // 65536 (multiple of 256)
    int t = blockIdx.x * 256 + threadIdx.x;
    if (t < total8) {
        int m = t >> 2;                  // Kpad=32 -> 4 ushort8 per row
        int k0 = (t & 3) * 8;
        ushort8_ vh, vl;
#pragma unroll
        for (int j = 0; j < 8; ++j) {
            int k = k0 + j;
            float v = (k < IN_) ? X[(size_t)m*IN_ + k] : 0.0f;
            unsigned short h = f2bf(v);
            vh[j] = h;
            vl[j] = f2bf(v - bf2f(h));
        }
        *(ushort8_*)(Xh + (size_t)m*32 + k0) = vh;
        *(ushort8_*)(Xl + (size_t)m*32 + k0) = vl;
        if (t < BN_) {
            const float* p = X + (size_t)t*IN_;
            float x = p[0], y = p[1], z = p[2];
            P4[t] = make_float4(x, y, z, x*x + y*y + z*z);
        }
    } else {
        int idx = t - total8;
        const int nWT = 2*64*32;         // 4096 (multiple of 256)
        if (idx < nWT) {
            int n = idx >> 5;            // row in WT (0..127)
            int k = idx & 31;
            float val = 0.0f;
            if (k < IN_) {
                if (n < 64) val = W1[(size_t)k*64 + n] - W1[(size_t)(IN_+k)*64 + n];
                else        val = W1[(size_t)(IN_+k)*64 + (n - 64)];
            }
            unsigned short h = f2bf(val);
            WTh[(size_t)n*32 + k] = h;
            WTl[(size_t)n*32 + k] = f2bf(val - bf2f(h));
        } else if (idx < nWT + 64) {
            int c = idx - nWT;
            cvec[c] = b1[c];             // layer 1: no BN shift folding
        }
    }
}

// ---------------- fused weight prep (layers 2,3): WT split-bf16 (BN fold) + c' vector ----------------
__global__ __launch_bounds__(256) void prep_layer(const float* __restrict__ W,
                                                  const float* __restrict__ scale,
                                                  const float* __restrict__ shift,
                                                  const float* __restrict__ bias,
                                                  unsigned short* __restrict__ WTh,
                                                  unsigned short* __restrict__ WTl,
                                                  float* __restrict__ cvec,
                                                  int Cin, int C, int Kpad) {
    int idx = blockIdx.x * 256 + threadIdx.x;
    int nWT = 2*C*Kpad;
    if (idx < nWT) {
        int n = idx / Kpad;
        int k = idx % Kpad;
        float val = 0.0f;
        if (k < Cin) {
            float s = scale[k];
            if (n < C) val = s * (W[(size_t)k*C + n] - W[(size_t)(Cin+k)*C + n]);
            else       val = s * W[(size_t)(Cin+k)*C + (n - C)];
        }
        unsigned short h = f2bf(val);
        WTh[(size_t)n*Kpad + k] = h;
        WTl[(size_t)n*Kpad + k] = f2bf(val - bf2f(h));
    } else if (idx < nWT + C) {
        int c = idx - nWT;
        float acc = bias[c];
        for (int d = 0; d < Cin; ++d) acc += shift[d] * W[(size_t)d*C + c];
        cvec[c] = acc;
    }
}

// ---------------- split-bf16 MFMA GEMM: PQ[M][Ntot] = X[M][K] @ WT^T, 128x128 tile, BK=32 ----------------
// 1-D grid, XCD-swizzled: all col-blocks of a row-panel land on XCD (y%8) for A-panel L2 reuse
__global__ __launch_bounds__(256) void mfma_dual(const unsigned short* __restrict__ Xh,
                                                 const unsigned short* __restrict__ Xl,
                                                 const unsigned short* __restrict__ WTh,
                                                 const unsigned short* __restrict__ WTl,
                                                 float* __restrict__ PQ, int K, int Ntot,
                                                 int gx) {
    __shared__ unsigned short sXh[128*32], sXl[128*32], sWh[128*32], sWl[128*32];
    int n = blockIdx.x;
    int by = (n & 7) + 8*(n/(8*gx));    // y%8 == n%8 == XCD
    int bx = (n >> 3) % gx;
    int tid = threadIdx.x, l = tid & 63, w = tid >> 6;
    int wr = w >> 1, wc = w & 1;                       // 2x2 waves -> 64x64 per wave
    int bm = by * 128, bn0 = bx * 128;

    f32x4_ acc[4][4];
#pragma unroll
    for (int i = 0; i < 4; ++i)
#pragma unroll
        for (int j = 0; j < 4; ++j) acc[i][j] = (f32x4_){0.f, 0.f, 0.f, 0.f};

    for (int k0 = 0; k0 < K; k0 += 32) {
#pragma unroll
        for (int i = 0; i < 2; ++i) {
            int idx = tid + i*256;                     // 0..511
            int row = idx >> 2;                        // 0..127
            int col0 = (idx & 3) * 8;                  // 0,8,16,24
            size_t gxo = (size_t)(bm  + row)*K + k0 + col0;
            size_t gwo = (size_t)(bn0 + row)*K + k0 + col0;
            int lo_ = ((row << 6) | (col0 << 1)) ^ ((row & 7) << 4);  // XOR swizzle
            *(ushort8_*)((char*)sXh + lo_) = *(const ushort8_*)(Xh + gxo);
            *(ushort8_*)((char*)sXl + lo_) = *(const ushort8_*)(Xl + gxo);
            *(ushort8_*)((char*)sWh + lo_) = *(const ushort8_*)(WTh + gwo);
            *(ushort8_*)((char*)sWl + lo_) = *(const ushort8_*)(WTl + gwo);
        }
        __syncthreads();

        int kb = (l >> 4) << 4;                        // byte offset of this lane's 8 k-elems
        bf16x8_ bh[4], bl4[4];
#pragma unroll
        for (int nf = 0; nf < 4; ++nf) {
            int rn = wc*64 + nf*16 + (l & 15);
            int o = ((rn << 6) | kb) ^ ((rn & 7) << 4);
            bh[nf]  = *(const bf16x8_*)((const char*)sWh + o);
            bl4[nf] = *(const bf16x8_*)((const char*)sWl + o);
        }
#pragma unroll
        for (int mf = 0; mf < 4; ++mf) {
            int rm = wr*64 + mf*16 + (l & 15);
            int o = ((rm << 6) | kb) ^ ((rm & 7) << 4);
            bf16x8_ ah = *(const bf16x8_*)((const char*)sXh + o);
            bf16x8_ al = *(const bf16x8_*)((const char*)sXl + o);
#pragma unroll
            for (int nf = 0; nf < 4; ++nf) {
                acc[mf][nf] = __builtin_amdgcn_mfma_f32_16x16x32_bf16(ah, bh[nf],  acc[mf][nf], 0, 0, 0);
                acc[mf][nf] = __builtin_amdgcn_mfma_f32_16x16x32_bf16(ah, bl4[nf], acc[mf][nf], 0, 0, 0);
                acc[mf][nf] = __builtin_amdgcn_mfma_f32_16x16x32_bf16(al, bh[nf],  acc[mf][nf], 0, 0, 0);
            }
        }
        __syncthreads();
    }

    int r0 = (l >> 4) << 2, cB = l & 15;
#pragma unroll
    for (int mf = 0; mf < 4; ++mf)
#pragma unroll
        for (int nf = 0; nf < 4; ++nf) {
            int col = bn0 + wc*64 + nf*16 + cB;
#pragma unroll
            for (int reg = 0; reg < 4; ++reg) {
                int row = bm + wr*64 + mf*16 + r0 + reg;
                PQ[(size_t)row*Ntot + col] = acc[mf][nf][reg];
            }
        }
}

// ---------------- edge combine: h = P[dst] + Q[src] + c ; lrelu; per-dst max -> split-bf16 X_next;
//                  BN partials (per-block stores, no atomics); per-block partial max ----------------
__global__ void combine_kernel(const float* __restrict__ P, const float* __restrict__ Q,
                               const float* __restrict__ cvec, const int* __restrict__ src,
                               unsigned short* __restrict__ Xh_out, unsigned short* __restrict__ Xl_out,
                               float* __restrict__ partial, float* __restrict__ gpart,
                               int C, int S) {
    int pb = blockIdx.x;
    int lb = (pb & 7) * CHUNKS_ + (pb >> 3);   // bijective: XCD (pb%8) gets all blocks of batch pb%8
    int c = threadIdx.x;                 // blockDim.x == C
    int i0 = lb * GRP;
    float cv = cvec[c];
    float sum = 0.f, ssq = 0.f;
    float bmx = -INFINITY;
    for (int g = 0; g < GRP; ++g) {
        int i = i0 + g;
        float p = P[(size_t)i*S + c] + cv;
        float mx = -INFINITY;
#pragma unroll
        for (int k = 0; k < K_; ++k) {
            int s = src[(size_t)i*K_ + k];
            float h = p + Q[(size_t)s*S + c];
            float l = (h >= 0.f) ? h : 0.2f*h;
            sum += l; ssq += l*l;
            mx = fmaxf(mx, l);
        }
        if (Xh_out) {                    // next layer's input, split-bf16 (Kpad_next == C)
            unsigned short hh = f2bf(mx);
            Xh_out[(size_t)i*C + c] = hh;
            Xl_out[(size_t)i*C + c] = f2bf(mx - bf2f(hh));
        }
        bmx = fmaxf(bmx, mx);
    }
    gpart[(size_t)lb*C + c] = bmx;
    partial[(size_t)lb*2*C + c]     = sum;
    partial[(size_t)lb*2*C + C + c] = ssq;
}

// ---------------- BN stats reduce -> scale/shift (deterministic tree) ----------------
__global__ __launch_bounds__(256) void reduce_kernel(const float* __restrict__ partial, int nblocks, int C,
                              const float* __restrict__ g, const float* __restrict__ be,
                              float* __restrict__ scale, float* __restrict__ shift) {
    int c = blockIdx.x;
    float s0 = 0.f, s1 = 0.f;
    for (int blk = threadIdx.x; blk < nblocks; blk += 256) {
        s0 += partial[(size_t)blk*2*C + c];
        s1 += partial[(size_t)blk*2*C + C + c];
    }
    __shared__ float l0[256], l1[256];
    l0[threadIdx.x] = s0; l1[threadIdx.x] = s1;
    __syncthreads();
    for (int off = 128; off > 0; off >>= 1) {
        if (threadIdx.x < off) {
            l0[threadIdx.x] += l0[threadIdx.x + off];
            l1[threadIdx.x] += l1[threadIdx.x + off];
        }
        __syncthreads();
    }
    if (threadIdx.x == 0) {
        float mean = l0[0] / (float)NEDGE_;
        float var  = l1[0] / (float)NEDGE_ - mean*mean;
        float sc = g[c] * rsqrtf(var + 1e-5f);
        scale[c] = sc;
        shift[c] = be[c] - mean*sc;
    }
}

// ---------------- fused global max-pool finalize ----------------
__global__ __launch_bounds__(1024) void gmax_finalize(
        const float* __restrict__ gp1, const float* __restrict__ gp2, const float* __restrict__ gp3,
        const float* __restrict__ sc1, const float* __restrict__ sh1,
        const float* __restrict__ sc2, const float* __restrict__ sh2,
        const float* __restrict__ sc3, const float* __restrict__ sh3,
        float* __restrict__ gfeat) {
    int b = blockIdx.x, grp = blockIdx.y;
    const float *gp, *sc, *sh; int C, c0, coff;
    if (grp == 0)      { gp = gp1; sc = sc1; sh = sh1; C = 64;  c0 = 0;            coff = 0;   }
    else if (grp <= 2) { gp = gp2; sc = sc2; sh = sh2; C = 128; c0 = (grp-1)*64;   coff = 64;  }
    else               { gp = gp3; sc = sc3; sh = sh3; C = 256; c0 = (grp-3)*64;   coff = 192; }
    int cl = threadIdx.x & 63;
    int stripe = threadIdx.x >> 6;   // 0..15
    int c = c0 + cl;
    float mx = -INFINITY;
    for (int ch = stripe; ch < CHUNKS_; ch += 16)
        mx = fmaxf(mx, gp[((size_t)b*CHUNKS_ + ch)*C + c]);
    __shared__ float red[16][64];
    red[stripe][cl] = mx;
    __syncthreads();
    for (int off = 8; off > 0; off >>= 1) {
        if (stripe < off) red[stripe][cl] = fmaxf(red[stripe][cl], red[stripe+off][cl]);
        __syncthreads();
    }
    if (stripe == 0)
        gfeat[b*448 + coff + c] = sc[c]*red[0][cl] + sh[c];
}

// ---------------- head part 1: H = BN(lrelu(gfeat@Wf1 + bf1)) ----------------
__global__ __launch_bounds__(256) void final1(const float* __restrict__ gfeat,
                                              const float* __restrict__ Wf1, const float* __restrict__ bf1,
                                              const float* __restrict__ gf, const float* __restrict__ bef,
                                              float* __restrict__ H) {
    __shared__ float gfs[B_][448];
    __shared__ float red[4][64][B_];
    int t = threadIdx.x;
    int cl = t & 63;
    int stripe = t >> 6;                 // 0..3
    int c = blockIdx.x * 64 + cl;
    for (int e = t; e < B_*448; e += 256) gfs[e/448][e%448] = gfeat[e];
    __syncthreads();
    float acc[B_] = {};
    for (int d = stripe*112; d < stripe*112 + 112; ++d) {
        float w = Wf1[(size_t)d*512 + c];
#pragma unroll
        for (int r = 0; r < B_; ++r) acc[r] += gfs[r][d] * w;
    }
#pragma unroll
    for (int r = 0; r < B_; ++r) red[stripe][cl][r] = acc[r];
    __syncthreads();
    if (stripe == 0) {
        float v[B_];
        float b1v = bf1[c];
#pragma unroll
        for (int r = 0; r < B_; ++r) {
            float a = red[0][cl][r] + red[1][cl][r] + red[2][cl][r] + red[3][cl][r] + b1v;
            v[r] = (a >= 0.f) ? a : 0.2f*a;
        }
        float mean = 0.f;
#pragma unroll
        for (int r = 0; r < B_; ++r) mean += v[r];
        mean *= (1.0f/B_);
        float var = 0.f;
#pragma unroll
        for (int r = 0; r < B_; ++r) { float dd = v[r] - mean; var += dd*dd; }
        var *= (1.0f/B_);
        float sc = gf[c] * rsqrtf(var + 1e-5f);
        float sh = bef[c] - mean*sc;
#pragma unroll
        for (int r = 0; r < B_; ++r) H[(size_t)r*512 + c] = v[r]*sc + sh;
    }
}

// ---------------- head part 2: out = H @ Wf2 + bf2 ----------------
__global__ __launch_bounds__(128) void final2(const float* __restrict__ H,
                                              const float* __restrict__ Wf2, const float* __restrict__ bf2,
                                              float* __restrict__ out) {
    int b = blockIdx.x, c = threadIdx.x;
    __shared__ float hs[512];
    for (int e = c; e < 512; e += 128) hs[e] = H[(size_t)b*512 + e];
    __syncthreads();
    float a = bf2[c];
    for (int d = 0; d < 512; ++d) a += hs[d] * Wf2[(size_t)d*128 + c];
    out[b*128 + c] = a;
}

// ---------------- host side ----------------
extern "C" void kernel_launch(void* const* d_in, const int* in_sizes, int n_in,
                              void* d_out, int out_size, void* d_ws, size_t ws_size,
                              hipStream_t stream) {
    (void)in_sizes; (void)n_in; (void)out_size; (void)ws_size;
    const float* points = (const float*)d_in[0];
    const float* W1 = (const float*)d_in[1];  const float* b1 = (const float*)d_in[2];
    const float* g1 = (const float*)d_in[3];  const float* be1 = (const float*)d_in[4];
    const float* W2 = (const float*)d_in[5];  const float* b2 = (const float*)d_in[6];
    const float* g2 = (const float*)d_in[7];  const float* be2 = (const float*)d_in[8];
    const float* W3 = (const float*)d_in[9];  const float* b3 = (const float*)d_in[10];
    const float* g3 = (const float*)d_in[11]; const float* be3 = (const float*)d_in[12];
    const float* Wf1 = (const float*)d_in[13]; const float* bf1 = (const float*)d_in[14];
    const float* gf = (const float*)d_in[15];  const float* bef = (const float*)d_in[16];
    const float* Wf2 = (const float*)d_in[17]; const float* bf2 = (const float*)d_in[18];
    float* out = (float*)d_out;

    size_t off = 0;
    char* base = (char*)d_ws;
    auto carve = [&](size_t bytes) -> void* {
        void* p = base + off;
        off += (bytes + 255) & ~(size_t)255;
        return p;
    };
    int*   src     = (int*)  carve((size_t)NEDGE_ * 4);
    float* PQ      = (float*)carve((size_t)BN_ * 512 * 4);   // 32MB; also kNN partial overlay
    float* gp1     = (float*)carve((size_t)(BN_/GRP) * 64 * 4);
    float* gp2     = (float*)carve((size_t)(BN_/GRP) * 128 * 4);
    float* gp3     = (float*)carve((size_t)(BN_/GRP) * 256 * 4);
    unsigned short* XhA = (unsigned short*)carve((size_t)BN_ * 128 * 2);
    unsigned short* XlA = (unsigned short*)carve((size_t)BN_ * 128 * 2);
    unsigned short* XhB = (unsigned short*)carve((size_t)BN_ * 128 * 2);
    unsigned short* XlB = (unsigned short*)carve((size_t)BN_ * 128 * 2);
    unsigned short* WTh = (unsigned short*)carve((size_t)512 * 128 * 2);
    unsigned short* WTl = (unsigned short*)carve((size_t)512 * 128 * 2);
    float4* P4     = (float4*)carve((size_t)BN_ * 16);
    float* cvec    = (float*)carve(256 * 4);
    float* sc1     = (float*)carve(64 * 4);
    float* sh1     = (float*)carve(64 * 4);
    float* sc2     = (float*)carve(128 * 4);
    float* sh2     = (float*)carve(128 * 4);
    float* sc3     = (float*)carve(256 * 4);
    float* sh3     = (float*)carve(256 * 4);
    float* partial = (float*)carve((size_t)(BN_/GRP) * 2 * 256 * 4);
    float* gfeat   = (float*)carve((size_t)B_ * 448 * 4);
    float* H       = (float*)carve((size_t)B_ * 512 * 4);

    // fused: cast layer-1 input + P4 pack + layer-1 weight prep
    // grid covers 65536 cast slots + 4096 WT1 slots + 64 cvec slots
    cast_prep1<<<(65536 + 4096 + 64 + 255)/256, 256, 0, stream>>>(
        points, XhA, XlA, P4, W1, b1, WTh, WTl, cvec);

    // kNN: phase-1 partials (SEG_*BN_*K_*8B = 32MB) overlay PQ (dead until first mfma_dual)
    unsigned long long* part = (unsigned long long*)PQ;
    knn_part<<<dim3(BN_/256, SEG_), 256, 0, stream>>>(P4, part);
    knn_merge<<<BN_/128, 128, 0, stream>>>(part, src);

    // ---- layer 1 (prep already done in cast_prep1) ----
    mfma_dual<<<1*(BN_/128), 256, 0, stream>>>(XhA, XlA, WTh, WTl, PQ, 32, 128, 1);
    combine_kernel<<<BN_/GRP, 64, 0, stream>>>(PQ, PQ + 64, cvec, src, XhB, XlB, partial, gp1, 64, 128);
    reduce_kernel<<<64, 256, 0, stream>>>(partial, BN_/GRP, 64, g1, be1, sc1, sh1);

    // ---- layer 2 ----
    prep_layer<<<(2*128*64 + 128 + 255)/256, 256, 0, stream>>>(W2, sc1, sh1, b2, WTh, WTl, cvec, 64, 128, 64);
    mfma_dual<<<2*(BN_/128), 256, 0, stream>>>(XhB, XlB, WTh, WTl, PQ, 64, 256, 2);
    combine_kernel<<<BN_/GRP, 128, 0, stream>>>(PQ, PQ + 128, cvec, src, XhA, XlA, partial, gp2, 128, 256);
    reduce_kernel<<<128, 256, 0, stream>>>(partial, BN_/GRP, 128, g2, be2, sc2, sh2);

    // ---- layer 3 ----
    prep_layer<<<(2*256*128 + 256 + 255)/256, 256, 0, stream>>>(W3, sc2, sh2, b3, WTh, WTl, cvec, 128, 256, 128);
    mfma_dual<<<4*(BN_/128), 256, 0, stream>>>(XhA, XlA, WTh, WTl, PQ, 128, 512, 4);
    combine_kernel<<<BN_/GRP, 256, 0, stream>>>(PQ, PQ + 256, cvec, src, nullptr, nullptr, partial, gp3, 256, 512);
    reduce_kernel<<<256, 256, 0, stream>>>(partial, BN_/GRP, 256, g3, be3, sc3, sh3);

    gmax_finalize<<<dim3(B_, 7), 1024, 0, stream>>>(gp1, gp2, gp3,
                                                    sc1, sh1, sc2, sh2, sc3, sh3, gfeat);

    final1<<<8, 256, 0, stream>>>(gfeat, Wf1, bf1, gf, bef, H);
    final2<<<8, 128, 0, stream>>>(H, Wf2, bf2, out);
}